// Round 2
// baseline (113.016 us; speedup 1.0000x reference)
//
#include <hip/hip_runtime.h>

#define NN 4096
#define MM 4096
#define NEG 0.01f

typedef float floatx4 __attribute__((ext_vector_type(4)));

// v2b: 2048 blocks x 256 threads; 2 rows/block, 2 waves per row (8 KB half-row
// per wave). No bulk LDS staging: accumulate s1 = sum w*(l+u), s2 = sum |w|*(u-l)
// and apply the 0.5 once at the end. l0/u0 (32 KB working set) come through
// L1/L2 per-lane; W loads are nontemporal (native ext_vector type — HIP float4
// is a struct and rejected by the builtin) so the 67 MB use-once stream doesn't
// evict them from L2. LDS reduced to 32 B for the cross-wave combine.
__global__ __launch_bounds__(256, 4) void abstract_leaky_relu_kernel(
    const float* __restrict__ lbnd,
    const float* __restrict__ ubnd,
    const float* __restrict__ alpha,
    const float* __restrict__ W,
    const float* __restrict__ b,
    const float* __restrict__ l0,
    const float* __restrict__ u0,
    float* __restrict__ out)
{
    __shared__ float pS1[4];
    __shared__ float pS2[4];

    const int wave = threadIdx.x >> 6;
    const int lane = threadIdx.x & 63;
    const int row  = (blockIdx.x << 1) + (wave >> 1);
    const int half = wave & 1;

    const float* __restrict__ Wr = W + (size_t)row * MM;
    const int base = (half << 11) + (lane << 2);

    float s1a = 0.f, s1b = 0.f, s2a = 0.f, s2b = 0.f;

    #pragma unroll
    for (int t = 0; t < 8; ++t) {
        const int j = base + t * 256;
        const floatx4 w = __builtin_nontemporal_load(
            reinterpret_cast<const floatx4*>(Wr + j));
        const float4 l = *reinterpret_cast<const float4*>(l0 + j);
        const float4 u = *reinterpret_cast<const float4*>(u0 + j);

        const float cx = l.x + u.x, cy = l.y + u.y;
        const float cz = l.z + u.z, cw = l.w + u.w;
        const float rx = u.x - l.x, ry = u.y - l.y;
        const float rz = u.z - l.z, rw = u.w - l.w;

        if (t & 1) {
            s1b += w.x * cx + w.y * cy + w.z * cz + w.w * cw;
            s2b += fabsf(w.x) * rx + fabsf(w.y) * ry +
                   fabsf(w.z) * rz + fabsf(w.w) * rw;
        } else {
            s1a += w.x * cx + w.y * cy + w.z * cz + w.w * cw;
            s2a += fabsf(w.x) * rx + fabsf(w.y) * ry +
                   fabsf(w.z) * rz + fabsf(w.w) * rw;
        }
    }

    float s1 = s1a + s1b;
    float s2 = s2a + s2b;

    #pragma unroll
    for (int off = 32; off > 0; off >>= 1) {
        s1 += __shfl_down(s1, off);
        s2 += __shfl_down(s2, off);
    }

    if (lane == 0) { pS1[wave] = s1; pS2[wave] = s2; }
    __syncthreads();

    if (threadIdx.x < 2) {
        const int r    = threadIdx.x;
        const int row2 = (blockIdx.x << 1) + r;

        const float S1 = pS1[2 * r] + pS1[2 * r + 1];
        const float S2 = pS2[2 * r] + pS2[2 * r + 1];
        const float Pu = 0.5f * (S1 + S2);   // max(W,0)@u0 + min(W,0)@l0
        const float Pl = 0.5f * (S1 - S2);   // max(W,0)@l0 + min(W,0)@u0

        const float L = lbnd[row2];
        const float U = ubnd[row2];
        const float A = alpha[row2];
        const float B = b[row2];

        float lw = NEG, uw = NEG, ub_bias = 0.0f;
        if (L > 0.0f) {
            lw = 1.0f; uw = 1.0f;
        } else if (L < 0.0f && U > 0.0f) {
            const float slope = (U - NEG * L) / (U - L);
            uw = slope;
            ub_bias = (NEG - slope) * L;     // crossing-neuron upper intercept
            lw = fminf(fmaxf(A, NEG), 1.0f);
        }

        out[row2]      = lw * (Pl + B);            // lower
        out[NN + row2] = uw * (Pu + B) + ub_bias;  // upper
    }
}

extern "C" void kernel_launch(void* const* d_in, const int* in_sizes, int n_in,
                              void* d_out, int out_size, void* d_ws, size_t ws_size,
                              hipStream_t stream) {
    const float* lbnd  = (const float*)d_in[0];
    const float* ubnd  = (const float*)d_in[1];
    const float* alpha = (const float*)d_in[2];
    const float* W     = (const float*)d_in[3];
    const float* b     = (const float*)d_in[4];
    const float* l0    = (const float*)d_in[5];
    const float* u0    = (const float*)d_in[6];
    float* out = (float*)d_out;

    abstract_leaky_relu_kernel<<<NN / 2, 256, 0, stream>>>(
        lbnd, ubnd, alpha, W, b, l0, u0, out);
}

// Round 3
// 107.510 us; speedup vs baseline: 1.0512x; 1.0512x over previous
//
#include <hip/hip_runtime.h>

#define NN 4096
#define MM 4096
#define NEG 0.01f
#define ROWS 4   // rows of W per block

// v3: register-resident c/r. 1024 blocks x 256 threads, 4 rows of W per block.
// Each wave owns a fixed quarter-row column slice [wave*1024, +1024); each lane
// holds its 16 c = 0.5*(l0+u0)... actually c = (l0+u0), r = (u0-l0) with the
// 0.5 folded into the epilogue. c/r live in 32 VGPRs, loaded ONCE per block.
// Steady state: exactly 1 VMEM instr per 16 B of W (16 independent float4
// loads per lane across the 4-row unroll), no LDS in the hot loop, no nt
// (W fits in the 256 MiB L3 across bench iterations).
__global__ __launch_bounds__(256, 4) void abstract_leaky_relu_kernel(
    const float* __restrict__ lbnd,
    const float* __restrict__ ubnd,
    const float* __restrict__ alpha,
    const float* __restrict__ W,
    const float* __restrict__ b,
    const float* __restrict__ l0,
    const float* __restrict__ u0,
    float* __restrict__ out)
{
    const int wave = threadIdx.x >> 6;
    const int lane = threadIdx.x & 63;
    const int row0 = blockIdx.x * ROWS;
    const int base = (wave << 10) + (lane << 2);   // this lane's column base

    // ---- load c/r into registers, once ----
    float4 c[4], r[4];
    #pragma unroll
    for (int q = 0; q < 4; ++q) {
        const int j = base + q * 256;
        const float4 l = *reinterpret_cast<const float4*>(l0 + j);
        const float4 u = *reinterpret_cast<const float4*>(u0 + j);
        c[q] = make_float4(l.x + u.x, l.y + u.y, l.z + u.z, l.w + u.w);
        r[q] = make_float4(u.x - l.x, u.y - l.y, u.z - l.z, u.w - l.w);
    }

    // ---- stream 4 rows of W against the register-resident c/r ----
    float s1[ROWS], s2[ROWS];
    #pragma unroll
    for (int rr = 0; rr < ROWS; ++rr) { s1[rr] = 0.f; s2[rr] = 0.f; }

    #pragma unroll
    for (int rr = 0; rr < ROWS; ++rr) {
        const float* __restrict__ Wr = W + (size_t)(row0 + rr) * MM + base;
        #pragma unroll
        for (int q = 0; q < 4; ++q) {
            const float4 w = *reinterpret_cast<const float4*>(Wr + q * 256);
            s1[rr] += w.x * c[q].x + w.y * c[q].y +
                      w.z * c[q].z + w.w * c[q].w;
            s2[rr] += fabsf(w.x) * r[q].x + fabsf(w.y) * r[q].y +
                      fabsf(w.z) * r[q].z + fabsf(w.w) * r[q].w;
        }
    }

    // ---- per-row wave reduction ----
    #pragma unroll
    for (int off = 32; off > 0; off >>= 1) {
        #pragma unroll
        for (int rr = 0; rr < ROWS; ++rr) {
            s1[rr] += __shfl_down(s1[rr], off);
            s2[rr] += __shfl_down(s2[rr], off);
        }
    }

    // ---- cross-wave combine ----
    __shared__ float pS1[4][ROWS];
    __shared__ float pS2[4][ROWS];
    if (lane == 0) {
        #pragma unroll
        for (int rr = 0; rr < ROWS; ++rr) {
            pS1[wave][rr] = s1[rr];
            pS2[wave][rr] = s2[rr];
        }
    }
    __syncthreads();

    if (threadIdx.x < ROWS) {
        const int rr  = threadIdx.x;
        const int row = row0 + rr;

        const float S1 = pS1[0][rr] + pS1[1][rr] + pS1[2][rr] + pS1[3][rr];
        const float S2 = pS2[0][rr] + pS2[1][rr] + pS2[2][rr] + pS2[3][rr];
        const float Pu = 0.5f * (S1 + S2);   // max(W,0)@u0 + min(W,0)@l0
        const float Pl = 0.5f * (S1 - S2);   // max(W,0)@l0 + min(W,0)@u0

        const float L = lbnd[row];
        const float U = ubnd[row];
        const float A = alpha[row];
        const float B = b[row];

        float lw = NEG, uw = NEG, ub_bias = 0.0f;
        if (L > 0.0f) {
            lw = 1.0f; uw = 1.0f;
        } else if (L < 0.0f && U > 0.0f) {
            const float slope = (U - NEG * L) / (U - L);
            uw = slope;
            ub_bias = (NEG - slope) * L;     // crossing-neuron upper intercept
            lw = fminf(fmaxf(A, NEG), 1.0f);
        }

        out[row]      = lw * (Pl + B);            // lower
        out[NN + row] = uw * (Pu + B) + ub_bias;  // upper
    }
}

extern "C" void kernel_launch(void* const* d_in, const int* in_sizes, int n_in,
                              void* d_out, int out_size, void* d_ws, size_t ws_size,
                              hipStream_t stream) {
    const float* lbnd  = (const float*)d_in[0];
    const float* ubnd  = (const float*)d_in[1];
    const float* alpha = (const float*)d_in[2];
    const float* W     = (const float*)d_in[3];
    const float* b     = (const float*)d_in[4];
    const float* l0    = (const float*)d_in[5];
    const float* u0    = (const float*)d_in[6];
    float* out = (float*)d_out;

    abstract_leaky_relu_kernel<<<NN / ROWS, 256, 0, stream>>>(
        lbnd, ubnd, alpha, W, b, l0, u0, out);
}

// Round 4
// 104.294 us; speedup vs baseline: 1.0836x; 1.0308x over previous
//
#include <hip/hip_runtime.h>

#define NN 4096
#define MM 4096
#define NEG 0.01f

// v4: v1's winning structure (LDS-staged c/r, one full contiguous 16 KB row of
// W per wave, 16 hoisted float4 loads, dual accumulators) with the prologue
// amortized: 512 blocks x 512 threads (8 waves), 8 rows per block. Staging of
// the 32 KB c/r LDS happens once per 8 rows (vs once per 4 in v1) and each CU
// runs 2 sequential blocks instead of 4 -> fewer dispatch gaps, higher W-stream
// duty cycle. The 0.5 factor is folded out of staging into the epilogue.
// 2 blocks/CU (64 KB LDS), 16 waves/CU.
__global__ __launch_bounds__(512, 4) void abstract_leaky_relu_kernel(
    const float* __restrict__ lbnd,
    const float* __restrict__ ubnd,
    const float* __restrict__ alpha,
    const float* __restrict__ W,
    const float* __restrict__ b,
    const float* __restrict__ l0,
    const float* __restrict__ u0,
    float* __restrict__ out)
{
    __shared__ float s_c[MM];
    __shared__ float s_r[MM];

    // stage c = (l0+u0), r = (u0-l0); 512 threads x 2 iterations
    for (int j = threadIdx.x * 4; j < MM; j += 512 * 4) {
        const float4 l = *reinterpret_cast<const float4*>(l0 + j);
        const float4 u = *reinterpret_cast<const float4*>(u0 + j);
        *reinterpret_cast<float4*>(s_c + j) =
            make_float4(l.x + u.x, l.y + u.y, l.z + u.z, l.w + u.w);
        *reinterpret_cast<float4*>(s_r + j) =
            make_float4(u.x - l.x, u.y - l.y, u.z - l.z, u.w - l.w);
    }
    __syncthreads();

    const int wave = threadIdx.x >> 6;          // 0..7
    const int lane = threadIdx.x & 63;
    const int row  = (blockIdx.x << 3) + wave;  // one full row per wave

    const float* __restrict__ Wr = W + (size_t)row * MM;
    const int base = lane * 4;

    float s1a = 0.f, s1b = 0.f, s2a = 0.f, s2b = 0.f;

    #pragma unroll
    for (int t = 0; t < 16; ++t) {
        const int j = base + t * 256;
        const float4 w = *reinterpret_cast<const float4*>(Wr + j);
        const float4 c = *reinterpret_cast<const float4*>(s_c + j);
        const float4 r = *reinterpret_cast<const float4*>(s_r + j);
        if (t & 1) {
            s1b += w.x * c.x + w.y * c.y + w.z * c.z + w.w * c.w;
            s2b += fabsf(w.x) * r.x + fabsf(w.y) * r.y +
                   fabsf(w.z) * r.z + fabsf(w.w) * r.w;
        } else {
            s1a += w.x * c.x + w.y * c.y + w.z * c.z + w.w * c.w;
            s2a += fabsf(w.x) * r.x + fabsf(w.y) * r.y +
                   fabsf(w.z) * r.z + fabsf(w.w) * r.w;
        }
    }

    float s1 = s1a + s1b;
    float s2 = s2a + s2b;

    #pragma unroll
    for (int off = 32; off > 0; off >>= 1) {
        s1 += __shfl_down(s1, off);
        s2 += __shfl_down(s2, off);
    }

    if (lane == 0) {
        const float Pu = 0.5f * (s1 + s2);   // max(W,0)@u0 + min(W,0)@l0
        const float Pl = 0.5f * (s1 - s2);   // max(W,0)@l0 + min(W,0)@u0

        const float L = lbnd[row];
        const float U = ubnd[row];
        const float A = alpha[row];
        const float B = b[row];

        float lw = NEG, uw = NEG, ub_bias = 0.0f;
        if (L > 0.0f) {
            lw = 1.0f; uw = 1.0f;
        } else if (L < 0.0f && U > 0.0f) {
            const float slope = (U - NEG * L) / (U - L);
            uw = slope;
            ub_bias = (NEG - slope) * L;     // crossing-neuron upper intercept
            lw = fminf(fmaxf(A, NEG), 1.0f);
        }

        out[row]      = lw * (Pl + B);            // lower
        out[NN + row] = uw * (Pu + B) + ub_bias;  // upper
    }
}

extern "C" void kernel_launch(void* const* d_in, const int* in_sizes, int n_in,
                              void* d_out, int out_size, void* d_ws, size_t ws_size,
                              hipStream_t stream) {
    const float* lbnd  = (const float*)d_in[0];
    const float* ubnd  = (const float*)d_in[1];
    const float* alpha = (const float*)d_in[2];
    const float* W     = (const float*)d_in[3];
    const float* b     = (const float*)d_in[4];
    const float* l0    = (const float*)d_in[5];
    const float* u0    = (const float*)d_in[6];
    float* out = (float*)d_out;

    abstract_leaky_relu_kernel<<<NN / 8, 512, 0, stream>>>(
        lbnd, ubnd, alpha, W, b, l0, u0, out);
}